// Round 1
// baseline (37.406 us; speedup 1.0000x reference)
//
#include <hip/hip_runtime.h>

// BatchedDynamicEmbeddingTablesV2: gather rows of a [CAPACITY, DIM] fp32
// table by slot index, then sum-pool each bag of BAG indices.
//   values : [CAPACITY * DIM] float32   (CAPACITY = 2097152, DIM = 64)
//   indices: [BATCH * BAG]    int       (BATCH = 16384, BAG = 50)
//   out    : [BATCH * DIM]    float32
//
// Memory-bound irregular gather: ~210 MB of 256 B row reads. Design:
//   - 16 threads per sample; thread owns one float4 (16 B) chunk of the row.
//     A quarter-wave (16 lanes) reads one full 256 B row coalesced.
//   - Block = 256 threads = 16 samples. Indices for the block staged in LDS
//     (800 ints) to avoid 16x redundant global index traffic.
//   - #pragma unroll 10 keeps ~10 independent dwordx4 loads in flight/wave.

#define EMB_DIM   64
#define EMB_BAG   50
#define SAMPLES_PER_BLOCK 16

__global__ __launch_bounds__(256) void embed_bag_pool_kernel(
    const float* __restrict__ values,
    const int*   __restrict__ indices,
    float*       __restrict__ out,
    int batch)
{
    __shared__ int s_idx[SAMPLES_PER_BLOCK * EMB_BAG];  // 800 ints = 3.2 KB

    const int sample0 = blockIdx.x * SAMPLES_PER_BLOCK;

    // Cooperative load of this block's 800 indices into LDS.
    for (int i = threadIdx.x; i < SAMPLES_PER_BLOCK * EMB_BAG; i += 256) {
        s_idx[i] = indices[(size_t)sample0 * EMB_BAG + i];
    }
    __syncthreads();

    const int local_s = threadIdx.x >> 4;   // 0..15  sample within block
    const int chunk   = threadIdx.x & 15;   // 0..15  float4 chunk within row

    const float4* __restrict__ v4 = (const float4*)values;
    const int* my_idx = &s_idx[local_s * EMB_BAG];

    float4 acc = make_float4(0.f, 0.f, 0.f, 0.f);

    #pragma unroll 10
    for (int j = 0; j < EMB_BAG; ++j) {
        const int idx = my_idx[j];
        const float4 r = v4[(size_t)idx * (EMB_DIM / 4) + chunk];
        acc.x += r.x;
        acc.y += r.y;
        acc.z += r.z;
        acc.w += r.w;
    }

    const int s = sample0 + local_s;
    if (s < batch) {
        ((float4*)out)[(size_t)s * (EMB_DIM / 4) + chunk] = acc;
    }
}

extern "C" void kernel_launch(void* const* d_in, const int* in_sizes, int n_in,
                              void* d_out, int out_size, void* d_ws, size_t ws_size,
                              hipStream_t stream) {
    const float* values  = (const float*)d_in[0];
    const int*   indices = (const int*)d_in[1];
    float*       out     = (float*)d_out;

    const int total_lookups = in_sizes[1];          // BATCH * BAG
    const int batch = total_lookups / EMB_BAG;      // 16384

    const int blocks = (batch + SAMPLES_PER_BLOCK - 1) / SAMPLES_PER_BLOCK;  // 1024
    embed_bag_pool_kernel<<<blocks, 256, 0, stream>>>(values, indices, out, batch);
}

// Round 2
// 36.558 us; speedup vs baseline: 1.0232x; 1.0232x over previous
//
#include <hip/hip_runtime.h>

// BatchedDynamicEmbeddingTablesV2: gather rows of a [CAPACITY, DIM] fp32
// table by slot index, then sum-pool each bag of BAG indices.
//   values : [CAPACITY * DIM] float32   (CAPACITY = 2097152, DIM = 64)
//   indices: [BATCH * BAG]    int       (BATCH = 16384, BAG = 50)
//   out    : [BATCH * DIM]    float32
//
// R2: occupancy experiment. 8 samples/block, bag split across two 16-lane
// half-groups (25 items each), combined via __shfl_xor(16). 2048 blocks,
// __launch_bounds__(256,8) keeps VGPR <= 64 so all 32 waves/CU are resident.
// Doubles outstanding-request concurrency vs R1 to test whether the 37 us
// was latency/parallelism-bound rather than HBM-BW-bound.

#define EMB_DIM   64
#define EMB_BAG   50
#define HALF_BAG  25
#define SAMPLES_PER_BLOCK 8

__global__ __launch_bounds__(256, 8) void embed_bag_pool_kernel(
    const float* __restrict__ values,
    const int*   __restrict__ indices,
    float*       __restrict__ out,
    int batch)
{
    __shared__ int s_idx[SAMPLES_PER_BLOCK * EMB_BAG];  // 400 ints = 1.6 KB

    const int sample0 = blockIdx.x * SAMPLES_PER_BLOCK;

    // Cooperative vectorized load of this block's 400 indices into LDS.
    // 400 ints = 100 int4; base offset = blockIdx * 1600 B (16B-aligned).
    const int4* __restrict__ gidx4 =
        (const int4*)(indices + (size_t)sample0 * EMB_BAG);
    int4* s_idx4 = (int4*)s_idx;
    if (threadIdx.x < SAMPLES_PER_BLOCK * EMB_BAG / 4) {
        s_idx4[threadIdx.x] = gidx4[threadIdx.x];
    }
    __syncthreads();

    const int local_s = threadIdx.x >> 5;         // 0..7   sample within block
    const int half    = (threadIdx.x >> 4) & 1;   // 0..1   bag half
    const int chunk   = threadIdx.x & 15;         // 0..15  float4 chunk in row

    const float4* __restrict__ v4 = (const float4*)values;
    const int* my_idx = &s_idx[local_s * EMB_BAG + half * HALF_BAG];

    float4 acc = make_float4(0.f, 0.f, 0.f, 0.f);

    #pragma unroll 5
    for (int j = 0; j < HALF_BAG; ++j) {
        const int idx = my_idx[j];
        const float4 r = v4[(size_t)idx * (EMB_DIM / 4) + chunk];
        acc.x += r.x;
        acc.y += r.y;
        acc.z += r.z;
        acc.w += r.w;
    }

    // Combine the two bag halves: partner lanes differ by 16 within the wave.
    acc.x += __shfl_xor(acc.x, 16);
    acc.y += __shfl_xor(acc.y, 16);
    acc.z += __shfl_xor(acc.z, 16);
    acc.w += __shfl_xor(acc.w, 16);

    const int s = sample0 + local_s;
    if (half == 0 && s < batch) {
        ((float4*)out)[(size_t)s * (EMB_DIM / 4) + chunk] = acc;
    }
}

extern "C" void kernel_launch(void* const* d_in, const int* in_sizes, int n_in,
                              void* d_out, int out_size, void* d_ws, size_t ws_size,
                              hipStream_t stream) {
    const float* values  = (const float*)d_in[0];
    const int*   indices = (const int*)d_in[1];
    float*       out     = (float*)d_out;

    const int total_lookups = in_sizes[1];          // BATCH * BAG
    const int batch = total_lookups / EMB_BAG;      // 16384

    const int blocks = (batch + SAMPLES_PER_BLOCK - 1) / SAMPLES_PER_BLOCK;  // 2048
    embed_bag_pool_kernel<<<blocks, 256, 0, stream>>>(values, indices, out, batch);
}